// Round 2
// baseline (147.071 us; speedup 1.0000x reference)
//
#include <hip/hip_runtime.h>
#include <cstdint>

#define NTOK 65536
#define DIM 240
#define KP 256
#define NMETA 600

typedef short bf16x8 __attribute__((ext_vector_type(8)));
typedef float f32x16 __attribute__((ext_vector_type(16)));

union U16B { uint4 u; bf16x8 v; };

__device__ __forceinline__ unsigned short f2bf(float x) {
  unsigned int u = __float_as_uint(x);
  u += 0x7fffu + ((u >> 16) & 1u);     // RNE
  return (unsigned short)(u >> 16);
}

// ---------------- kernel 1: pack expert weights to bf16 [8][256][256], bias fused at k=240
__global__ __launch_bounds__(256) void prep_w(const float* __restrict__ ew,
                                              const float* __restrict__ eb,
                                              unsigned short* __restrict__ Wb) {
  int idx = blockIdx.x * 256 + threadIdx.x;     // 131072 threads, 4 k's each
  int k0 = (idx & 63) << 2;
  int n  = (idx >> 6) & 255;
  int e  = idx >> 14;
  ushort4 v = {0, 0, 0, 0};
  if (n < DIM) {
    float f0 = 0.f, f1 = 0.f, f2 = 0.f, f3 = 0.f;
    const float* wrow = ew + (e * DIM + n) * DIM;
    if (k0 < DIM) { f0 = wrow[k0]; f1 = wrow[k0 + 1]; f2 = wrow[k0 + 2]; f3 = wrow[k0 + 3]; }
    else if (k0 == DIM) { f0 = eb[e * DIM + n]; }   // bias column
    v.x = f2bf(f0); v.y = f2bf(f1); v.z = f2bf(f2); v.w = f2bf(f3);
  }
  *(ushort4*)&Wb[(size_t)idx * 4] = v;
}

// ---------------- kernel 2: gating + x -> bf16 padded [NTOK][256] + pair id / weights / histogram
__global__ __launch_bounds__(256) void gating(const float* __restrict__ x,
                                              const float* __restrict__ gw,
                                              const float* __restrict__ gb,
                                              unsigned short* __restrict__ xbp,
                                              unsigned char* __restrict__ pairid,
                                              float2* __restrict__ wpair,
                                              int* __restrict__ cnt) {
  __shared__ __align__(16) float gwT[8 * DIM];
  __shared__ int hist[64];
  for (int i = threadIdx.x; i < 8 * DIM; i += 256) gwT[(i & 7) * DIM + (i >> 3)] = gw[i];
  if (threadIdx.x < 64) hist[threadIdx.x] = 0;
  __syncthreads();
  const int lane = threadIdx.x & 63;
  const int wav = (blockIdx.x << 2) + (threadIdx.x >> 6);   // 16384 waves
  float gbv[8];
#pragma unroll
  for (int e = 0; e < 8; ++e) gbv[e] = gb[e];
  for (int t = wav; t < NTOK; t += 16384) {
    float p[8];
#pragma unroll
    for (int e = 0; e < 8; ++e) p[e] = 0.f;
    float4 xv = make_float4(0.f, 0.f, 0.f, 0.f);
    if (lane < 60) {
      xv = *(const float4*)(x + (size_t)t * DIM + lane * 4);
#pragma unroll
      for (int e = 0; e < 8; ++e) {
        const float4 g = *(const float4*)(gwT + e * DIM + lane * 4);
        p[e] += xv.x * g.x + xv.y * g.y + xv.z * g.z + xv.w * g.w;
      }
    }
#pragma unroll
    for (int m = 1; m < 64; m <<= 1) {
#pragma unroll
      for (int e = 0; e < 8; ++e) p[e] += __shfl_xor(p[e], m, 64);
    }
    float l[8];
#pragma unroll
    for (int e = 0; e < 8; ++e) l[e] = p[e] + gbv[e];
    int i1 = 0; float b1 = l[0];
#pragma unroll
    for (int e = 1; e < 8; ++e) if (l[e] > b1) { b1 = l[e]; i1 = e; }
    int i2 = -1; float b2 = -3.0e38f;
#pragma unroll
    for (int e = 0; e < 8; ++e) if (e != i1 && l[e] > b2) { b2 = l[e]; i2 = e; }
    // top-2 softmax renorm: w1 = 1/(1+exp(l2-l1))
    float q = expf(b2 - b1);
    float w1 = 1.f / (1.f + q);
    float w2 = q / (1.f + q);
    ushort4 v = {0, 0, 0, 0};
    if (lane < 60) { v.x = f2bf(xv.x); v.y = f2bf(xv.y); v.z = f2bf(xv.z); v.w = f2bf(xv.w); }
    else if (lane == 60) v.x = 0x3F80;          // x[240] = 1.0 (bias column)
    *(ushort4*)(xbp + (size_t)t * KP + lane * 4) = v;
    const int elo = (i1 < i2) ? i1 : i2;
    const int ehi = (i1 < i2) ? i2 : i1;
    const float wlo = (i1 < i2) ? w1 : w2;
    const float whi = (i1 < i2) ? w2 : w1;
    const int pp = elo * 8 + ehi;
    if (lane == 0) {
      pairid[t] = (unsigned char)pp;
      wpair[t] = make_float2(wlo, whi);
      atomicAdd(&hist[pp], 1);
    }
  }
  __syncthreads();
  if (threadIdx.x < 64 && hist[threadIdx.x] > 0) atomicAdd(&cnt[threadIdx.x], hist[threadIdx.x]);
}

// ---------------- kernel 3: scan buckets -> cursors + per-block meta (1 block, 64 threads)
__global__ void scan_k(const int* __restrict__ cnt, int* __restrict__ gcur,
                       int4* __restrict__ meta) {
  __shared__ int sc[64], sstart[64], stile[64], stot;
  const int tid = threadIdx.x;
  sc[tid] = cnt[tid];
  __syncthreads();
  if (tid == 0) {
    int a = 0, ta = 0;
    for (int p = 0; p < 64; ++p) { sstart[p] = a; stile[p] = ta; a += sc[p]; ta += (sc[p] + 127) >> 7; }
    stot = ta;
  }
  __syncthreads();
  gcur[tid] = sstart[tid];
  const int c = sc[tid], e0 = tid >> 3, e1 = tid & 7;
  for (int i = 0; (i << 7) < c; ++i)
    meta[stile[tid] + i] = make_int4(e0, e1, sstart[tid] + (i << 7), min(128, c - (i << 7)));
  for (int j = stot + tid; j < NMETA; j += 64)
    meta[j] = make_int4(0, 0, 0, 0);
}

// ---------------- kernel 4: scatter token indices into pair buckets
__global__ __launch_bounds__(256) void scatter_k(const unsigned char* __restrict__ pairid,
                                                 int* __restrict__ gcur,
                                                 int* __restrict__ perm) {
  __shared__ int lcnt[64], lbase[64];
  const int tid = threadIdx.x;
  if (tid < 64) lcnt[tid] = 0;
  __syncthreads();
  const int t = blockIdx.x * 256 + tid;
  const int p = pairid[t];
  const int rank = atomicAdd(&lcnt[p], 1);
  __syncthreads();
  if (tid < 64 && lcnt[tid] > 0) lbase[tid] = atomicAdd(&gcur[tid], lcnt[tid]);
  __syncthreads();
  perm[lbase[p] + rank] = t;
}

// ---------------- kernel 5: pair-sparse MoE GEMM (128 tokens x 256 cols per block)
#define GLDS16(g, l)                                                        \
  __builtin_amdgcn_global_load_lds(                                         \
      (__attribute__((address_space(1))) unsigned int*)(g),                 \
      (__attribute__((address_space(3))) unsigned int*)(l), 16, 0, 0)

__global__ __launch_bounds__(256, 2) void moe_gemm_pair(const unsigned short* __restrict__ xbp,
                                                        const unsigned short* __restrict__ Wb,
                                                        const float2* __restrict__ wpair,
                                                        const int* __restrict__ perm,
                                                        const int4* __restrict__ meta,
                                                        float* __restrict__ out) {
  __shared__ __align__(16) char alds[16384];   // [128 rows][64 k] bf16, src-swizzled
  __shared__ __align__(16) char wlds[32768];   // [256 n][64 k] bf16, src-swizzled
  __shared__ int ptok[128];
  __shared__ float wrt[128], wfin[128];

  const int4 m = meta[blockIdx.x];
  const int n = m.w;
  if (n == 0) return;
  const int tid = threadIdx.x;
  const int lane = tid & 63;
  const int wid = tid >> 6;
  const int wr = wid >> 1, wc = wid & 1;
  const int l31 = lane & 31, hi = lane >> 5;

  if (tid < 128) {
    const int idx = m.z + (tid < n ? tid : n - 1);
    const int t = perm[idx];
    ptok[tid] = t;
    const float2 w2 = wpair[t];
    wrt[tid] = w2.x / w2.y;     // wlo/whi
    wfin[tid] = w2.y;           // whi
  }
  __syncthreads();

  f32x16 acc[2][4] = {};

  for (int it = 0; it < 8; ++it) {
    const int e = (it < 4) ? m.x : m.y;
    const int kc = it & 3;
    // stage A (gathered rows) : 4 rounds x 4 KB
#pragma unroll
    for (int j = 0; j < 4; ++j) {
      const int o = tid * 16 + j * 4096;
      const int r = o >> 7, b = o & 127;
      GLDS16((const char*)xbp + (size_t)ptok[r] * 512 + kc * 128 + (b ^ ((r & 7) << 4)),
             alds + o);
    }
    // stage W chunk: 8 rounds x 4 KB
#pragma unroll
    for (int j = 0; j < 8; ++j) {
      const int o = tid * 16 + j * 4096;
      const int r = o >> 7, b = o & 127;
      GLDS16((const char*)Wb + (size_t)e * 131072 + (size_t)r * 512 + kc * 128 + (b ^ ((r & 7) << 4)),
             wlds + o);
    }
    if (it == 4) {
      // between expert passes: acc *= wlo/whi (per output row)
#pragma unroll
      for (int rf = 0; rf < 2; ++rf) {
#pragma unroll
        for (int r = 0; r < 16; ++r) {
          const int rw = wr * 64 + rf * 32 + (r & 3) + ((r >> 2) << 3) + (hi << 2);
          const float s = wrt[rw];
#pragma unroll
          for (int cf = 0; cf < 4; ++cf) acc[rf][cf][r] *= s;
        }
      }
    }
    __syncthreads();          // drains vmcnt(0): staged data visible
#pragma unroll
    for (int ks = 0; ks < 4; ++ks) {
      const int sx = (ks * 32 + (hi << 4)) ^ ((lane & 7) << 4);
      U16B a0, a1;
      a0.u = *(const uint4*)(alds + ((wr * 64 + l31) << 7) + sx);
      a1.u = *(const uint4*)(alds + ((wr * 64 + 32 + l31) << 7) + sx);
#pragma unroll
      for (int cf = 0; cf < 4; ++cf) {
        U16B b; b.u = *(const uint4*)(wlds + ((wc * 128 + cf * 32 + l31) << 7) + sx);
        acc[0][cf] = __builtin_amdgcn_mfma_f32_32x32x16_bf16(a0.v, b.v, acc[0][cf], 0, 0, 0);
        acc[1][cf] = __builtin_amdgcn_mfma_f32_32x32x16_bf16(a1.v, b.v, acc[1][cf], 0, 0, 0);
      }
    }
    __syncthreads();          // all waves done reading before next stage overwrites
  }

  // epilogue: out[tok,col] = whi * acc
#pragma unroll
  for (int cf = 0; cf < 4; ++cf) {
    const int col = wc * 128 + cf * 32 + l31;
    if (col < DIM) {
#pragma unroll
      for (int rf = 0; rf < 2; ++rf) {
#pragma unroll
        for (int r = 0; r < 16; ++r) {
          const int rw = wr * 64 + rf * 32 + (r & 3) + ((r >> 2) << 3) + (hi << 2);
          if (rw < n) out[(size_t)ptok[rw] * DIM + col] = wfin[rw] * acc[rf][cf][r];
        }
      }
    }
  }
}

extern "C" void kernel_launch(void* const* d_in, const int* in_sizes, int n_in,
                              void* d_out, int out_size, void* d_ws, size_t ws_size,
                              hipStream_t stream) {
  const float* x  = (const float*)d_in[0];
  const float* gw = (const float*)d_in[1];
  const float* gb = (const float*)d_in[2];
  const float* ew = (const float*)d_in[3];
  const float* eb = (const float*)d_in[4];
  float* out = (float*)d_out;

  // workspace layout
  char* ws = (char*)d_ws;
  unsigned short* Wb   = (unsigned short*)ws;                       // 1 MB
  unsigned short* xbp  = (unsigned short*)(ws + (1u << 20));        // 32 MB
  float2*         wpr  = (float2*)(ws + (33u << 20));               // 512 KB
  int*            perm = (int*)(ws + (33u << 20) + (512u << 10));   // 256 KB
  unsigned char*  pid  = (unsigned char*)(ws + (33u << 20) + (768u << 10)); // 64 KB
  int*            cnt  = (int*)(ws + (33u << 20) + (832u << 10));   // 256 B
  int*            gcur = (int*)(ws + (33u << 20) + (833u << 10));   // 256 B
  int4*           meta = (int4*)(ws + (33u << 20) + (834u << 10));  // 9.6 KB

  hipMemsetAsync(cnt, 0, 64 * sizeof(int), stream);
  prep_w<<<512, 256, 0, stream>>>(ew, eb, Wb);
  gating<<<4096, 256, 0, stream>>>(x, gw, gb, xbp, pid, wpr, cnt);
  scan_k<<<1, 64, 0, stream>>>(cnt, gcur, meta);
  scatter_k<<<256, 256, 0, stream>>>(pid, gcur, perm);
  moe_gemm_pair<<<NMETA, 256, 0, stream>>>(xbp, Wb, wpr, perm, meta, out);
}

// Round 3
// 118.387 us; speedup vs baseline: 1.2423x; 1.2423x over previous
//
#include <hip/hip_runtime.h>
#include <cstdint>

#define NTOK 65536
#define DIM 240
#define KP 256
#define NMETA 600

typedef short bf16x8 __attribute__((ext_vector_type(8)));
typedef float f32x16 __attribute__((ext_vector_type(16)));

union U16B { uint4 u; bf16x8 v; };

__device__ __forceinline__ unsigned short f2bf(float x) {
  unsigned int u = __float_as_uint(x);
  u += 0x7fffu + ((u >> 16) & 1u);     // RNE
  return (unsigned short)(u >> 16);
}

// ---------------- kernel 1: pack expert weights to bf16 [8][256][256], bias fused at k=240
__global__ __launch_bounds__(256) void prep_w(const float* __restrict__ ew,
                                              const float* __restrict__ eb,
                                              unsigned short* __restrict__ Wb) {
  int idx = blockIdx.x * 256 + threadIdx.x;     // 131072 threads, 4 k's each
  int k0 = (idx & 63) << 2;
  int n  = (idx >> 6) & 255;
  int e  = idx >> 14;
  ushort4 v = {0, 0, 0, 0};
  if (n < DIM) {
    float f0 = 0.f, f1 = 0.f, f2 = 0.f, f3 = 0.f;
    const float* wrow = ew + (e * DIM + n) * DIM;
    if (k0 < DIM) { f0 = wrow[k0]; f1 = wrow[k0 + 1]; f2 = wrow[k0 + 2]; f3 = wrow[k0 + 3]; }
    else if (k0 == DIM) { f0 = eb[e * DIM + n]; }   // bias column
    v.x = f2bf(f0); v.y = f2bf(f1); v.z = f2bf(f2); v.w = f2bf(f3);
  }
  *(ushort4*)&Wb[(size_t)idx * 4] = v;
}

// ---------------- kernel 2: gating (one wave per token) + x -> bf16 padded [NTOK][256]
__global__ __launch_bounds__(256) void gating(const float* __restrict__ x,
                                              const float* __restrict__ gw,
                                              const float* __restrict__ gb,
                                              unsigned short* __restrict__ xbp,
                                              float* __restrict__ cw) {
  __shared__ __align__(16) float gwT[8][DIM];
  for (int i = threadIdx.x; i < 8 * DIM; i += 256) gwT[i & 7][i >> 3] = gw[i];
  __syncthreads();
  const int lane = threadIdx.x & 63;
  const int wav = (blockIdx.x << 2) + (threadIdx.x >> 6);   // 16384 waves
  const bool act = lane < 60;
  // hoisted, token-loop-invariant gate fragments (32 VGPRs) + biases
  float4 g[8]; float gbv[8];
#pragma unroll
  for (int e = 0; e < 8; ++e) {
    g[e] = act ? *(const float4*)(&gwT[e][lane * 4]) : make_float4(0.f, 0.f, 0.f, 0.f);
    gbv[e] = gb[e];
  }
  for (int t = wav; t < NTOK; t += 16384) {
    float4 xv = act ? *(const float4*)(x + (size_t)t * DIM + lane * 4)
                    : make_float4(0.f, 0.f, 0.f, 0.f);
    float p[8];
#pragma unroll
    for (int e = 0; e < 8; ++e)
      p[e] = xv.x * g[e].x + xv.y * g[e].y + xv.z * g[e].z + xv.w * g[e].w;
#pragma unroll
    for (int m = 1; m < 64; m <<= 1) {
#pragma unroll
      for (int e = 0; e < 8; ++e) p[e] += __shfl_xor(p[e], m, 64);
    }
    float l[8];
#pragma unroll
    for (int e = 0; e < 8; ++e) l[e] = p[e] + gbv[e];
    int i1 = 0; float b1 = l[0];
#pragma unroll
    for (int e = 1; e < 8; ++e) if (l[e] > b1) { b1 = l[e]; i1 = e; }
    int i2 = -1; float b2 = -3.0e38f;
#pragma unroll
    for (int e = 0; e < 8; ++e) if (e != i1 && l[e] > b2) { b2 = l[e]; i2 = e; }
    float q = expf(b2 - b1);
    float w1 = 1.f / (1.f + q);
    float w2 = q / (1.f + q);
    ushort4 v = {0, 0, 0, 0};
    if (act) { v.x = f2bf(xv.x); v.y = f2bf(xv.y); v.z = f2bf(xv.z); v.w = f2bf(xv.w); }
    else if (lane == 60) v.x = 0x3F80;          // x[240] = 1.0 (bias column)
    *(ushort4*)(xbp + (size_t)t * KP + lane * 4) = v;
    if (lane < 8) cw[(size_t)t * 8 + lane] = (lane == i1) ? w1 : ((lane == i2) ? w2 : 0.f);
  }
}

// ---------------- kernel 3: per-token pair extraction + histogram
__global__ __launch_bounds__(256) void pairize(const float* __restrict__ cw,
                                               unsigned char* __restrict__ pairid,
                                               float2* __restrict__ wpair,
                                               int* __restrict__ cnt) {
  __shared__ int hist[64];
  const int tid = threadIdx.x;
  if (tid < 64) hist[tid] = 0;
  __syncthreads();
  const int t = blockIdx.x * 256 + tid;
  float w[8];
  *(float4*)(w)     = *(const float4*)(cw + (size_t)t * 8);
  *(float4*)(w + 4) = *(const float4*)(cw + (size_t)t * 8 + 4);
  int ea = -1, eb = -1; float wa = 0.f, wb = 0.f;
#pragma unroll
  for (int e = 0; e < 8; ++e) {
    if (w[e] > 0.f) {
      if (ea < 0) { ea = e; wa = w[e]; } else { eb = e; wb = w[e]; }
    }
  }
  if (ea < 0) { ea = 0; wa = 1.f; }             // unreachable safety
  if (eb < 0) {                                  // top-2 weight underflowed to 0
    eb = (ea == 7) ? 6 : 7; wb = 0.f;
    if (eb < ea) { int te = ea; ea = eb; eb = te; float tw = wa; wa = wb; wb = tw; }
  }
  const int pp = ea * 8 + eb;
  pairid[t] = (unsigned char)pp;
  wpair[t] = make_float2(wa, wb);               // (weight of min-idx, weight of max-idx)
  atomicAdd(&hist[pp], 1);
  __syncthreads();
  if (tid < 64 && hist[tid] > 0) atomicAdd(&cnt[tid], hist[tid]);
}

// ---------------- kernel 4: scan buckets -> cursors + per-tile meta (1 block, 64 threads)
__global__ void scan_k(const int* __restrict__ cnt, int* __restrict__ gcur,
                       int4* __restrict__ meta) {
  __shared__ int sc[64], sstart[64], stile[64], stot;
  const int tid = threadIdx.x;
  sc[tid] = cnt[tid];
  __syncthreads();
  if (tid == 0) {
    int a = 0, ta = 0;
    for (int p = 0; p < 64; ++p) { sstart[p] = a; stile[p] = ta; a += sc[p]; ta += (sc[p] + 127) >> 7; }
    stot = ta;
  }
  __syncthreads();
  gcur[tid] = sstart[tid];
  const int c = sc[tid], e0 = tid >> 3, e1 = tid & 7;
  for (int i = 0; (i << 7) < c; ++i)
    meta[stile[tid] + i] = make_int4(e0, e1, sstart[tid] + (i << 7), min(128, c - (i << 7)));
  for (int j = stot + tid; j < NMETA; j += 64)
    meta[j] = make_int4(0, 0, 0, 0);
}

// ---------------- kernel 5: scatter token indices into pair buckets
__global__ __launch_bounds__(256) void scatter_k(const unsigned char* __restrict__ pairid,
                                                 int* __restrict__ gcur,
                                                 int* __restrict__ perm) {
  __shared__ int lcnt[64], lbase[64];
  const int tid = threadIdx.x;
  if (tid < 64) lcnt[tid] = 0;
  __syncthreads();
  const int t = blockIdx.x * 256 + tid;
  const int p = pairid[t];
  const int rank = atomicAdd(&lcnt[p], 1);
  __syncthreads();
  if (tid < 64 && lcnt[tid] > 0) lbase[tid] = atomicAdd(&gcur[tid], lcnt[tid]);
  __syncthreads();
  perm[lbase[p] + rank] = t;
}

// ---------------- kernel 6: pair-sparse MoE GEMM, 128 tok x 128 col tiles, dbuf pipeline
#define GLDS16(g, l)                                                        \
  __builtin_amdgcn_global_load_lds(                                         \
      (__attribute__((address_space(1))) unsigned int*)(g),                 \
      (__attribute__((address_space(3))) unsigned int*)(l), 16, 0, 0)

__global__ __launch_bounds__(256, 2) void moe_gemm_pair(const unsigned short* __restrict__ xbp,
                                                        const unsigned short* __restrict__ Wb,
                                                        const float2* __restrict__ wpair,
                                                        const int* __restrict__ perm,
                                                        const int4* __restrict__ meta,
                                                        float* __restrict__ out) {
  extern __shared__ __align__(16) char smem[];
  // [0,32K): A dbuf (2 x 16K)  [32K,64K): W dbuf (2 x 16K)  then ptok[128], wab[128]
  int* ptok = (int*)(smem + 65536);
  float2* wab = (float2*)(smem + 66048);

  const int4 m = meta[blockIdx.x >> 1];
  const int n = m.w;
  if (n == 0) return;
  const int ch = blockIdx.x & 1;                 // column half: cols [ch*128, ch*128+128)
  const int tid = threadIdx.x, lane = tid & 63, wid = tid >> 6;
  const int wr = wid >> 1, wc = wid & 1;         // 2x2 wave grid, wave tile 64x64
  const int l31 = lane & 31, hi = lane >> 5;

  if (tid < 128) {
    const int t = perm[m.z + (tid < n ? tid : n - 1)];
    ptok[tid] = t;
    wab[tid] = wpair[t];
  }
  __syncthreads();

  // staging geometry: thread covers rows srow + j*32, byte slot sb (swizzled)
  const int srow = tid >> 3;
  const int sb = (tid & 7) * 16;
  const int sxz = sb ^ ((srow & 7) << 4);
  const char* asrc[4]; const char* wsrc[4];
#pragma unroll
  for (int j = 0; j < 4; ++j) {
    const int r = srow + j * 32;                 // r & 7 == srow & 7
    asrc[j] = (const char*)xbp + (size_t)ptok[r] * 512 + sxz;
    wsrc[j] = (const char*)Wb + (size_t)(ch * 128 + r) * 512 + sxz;
  }
  const int ldst = tid * 16;

  // prologue: stage it=0 (expert m.x, kc=0) into buffer 0
#pragma unroll
  for (int j = 0; j < 4; ++j) GLDS16(asrc[j], smem + ldst + j * 4096);
#pragma unroll
  for (int j = 0; j < 4; ++j) GLDS16(wsrc[j] + (size_t)m.x * 131072, smem + 32768 + ldst + j * 4096);
  __syncthreads();

  f32x16 accA[2][2] = {}, accB[2][2] = {};

  for (int it = 0; it < 8; ++it) {               // it<4: expert m.x -> accA; else m.y -> accB
    const int cur = it & 1;
    if (it < 7) {                                // prefetch next chunk into other buffer
      const int nx = it + 1;
      const int koff = (nx & 3) * 128;
      const size_t eoff = (size_t)((nx < 4) ? m.x : m.y) * 131072;
      char* an = smem + ((cur ^ 1) << 14);
      char* wn = smem + 32768 + ((cur ^ 1) << 14);
#pragma unroll
      for (int j = 0; j < 4; ++j) GLDS16(asrc[j] + koff, an + ldst + j * 4096);
#pragma unroll
      for (int j = 0; j < 4; ++j) GLDS16(wsrc[j] + eoff + koff, wn + ldst + j * 4096);
    }
    const char* ac = smem + (cur << 14);
    const char* wcp = smem + 32768 + (cur << 14);
#pragma unroll
    for (int ks = 0; ks < 4; ++ks) {
      const int sx = (ks * 32 + (hi << 4)) ^ ((lane & 7) << 4);
      U16B a0, a1, b0, b1;
      a0.u = *(const uint4*)(ac + ((wr * 64 + l31) << 7) + sx);
      a1.u = *(const uint4*)(ac + ((wr * 64 + 32 + l31) << 7) + sx);
      b0.u = *(const uint4*)(wcp + ((wc * 64 + l31) << 7) + sx);
      b1.u = *(const uint4*)(wcp + ((wc * 64 + 32 + l31) << 7) + sx);
      if (it < 4) {
        accA[0][0] = __builtin_amdgcn_mfma_f32_32x32x16_bf16(a0.v, b0.v, accA[0][0], 0, 0, 0);
        accA[0][1] = __builtin_amdgcn_mfma_f32_32x32x16_bf16(a0.v, b1.v, accA[0][1], 0, 0, 0);
        accA[1][0] = __builtin_amdgcn_mfma_f32_32x32x16_bf16(a1.v, b0.v, accA[1][0], 0, 0, 0);
        accA[1][1] = __builtin_amdgcn_mfma_f32_32x32x16_bf16(a1.v, b1.v, accA[1][1], 0, 0, 0);
      } else {
        accB[0][0] = __builtin_amdgcn_mfma_f32_32x32x16_bf16(a0.v, b0.v, accB[0][0], 0, 0, 0);
        accB[0][1] = __builtin_amdgcn_mfma_f32_32x32x16_bf16(a0.v, b1.v, accB[0][1], 0, 0, 0);
        accB[1][0] = __builtin_amdgcn_mfma_f32_32x32x16_bf16(a1.v, b0.v, accB[1][0], 0, 0, 0);
        accB[1][1] = __builtin_amdgcn_mfma_f32_32x32x16_bf16(a1.v, b1.v, accB[1][1], 0, 0, 0);
      }
    }
    __syncthreads();   // drains vmcnt(0): prefetch landed (covered by compute), bufs released
  }

  // epilogue: out[tok, col] = wa*accA + wb*accB
#pragma unroll
  for (int cf = 0; cf < 2; ++cf) {
    const int col = ch * 128 + wc * 64 + cf * 32 + l31;
    if (col < DIM) {
#pragma unroll
      for (int rf = 0; rf < 2; ++rf) {
#pragma unroll
        for (int r = 0; r < 16; ++r) {
          const int rw = wr * 64 + rf * 32 + (r & 3) + ((r >> 2) << 3) + (hi << 2);
          if (rw < n) {
            const float2 w2 = wab[rw];
            out[(size_t)ptok[rw] * DIM + col] = w2.x * accA[rf][cf][r] + w2.y * accB[rf][cf][r];
          }
        }
      }
    }
  }
}

extern "C" void kernel_launch(void* const* d_in, const int* in_sizes, int n_in,
                              void* d_out, int out_size, void* d_ws, size_t ws_size,
                              hipStream_t stream) {
  const float* x  = (const float*)d_in[0];
  const float* gw = (const float*)d_in[1];
  const float* gb = (const float*)d_in[2];
  const float* ew = (const float*)d_in[3];
  const float* eb = (const float*)d_in[4];
  float* out = (float*)d_out;

  // workspace layout
  char* ws = (char*)d_ws;
  unsigned short* Wb   = (unsigned short*)ws;                        // 1 MB
  unsigned short* xbp  = (unsigned short*)(ws + (1u << 20));         // 32 MB
  float*          cw   = (float*)(ws + (33u << 20));                 // 2 MB
  float2*         wpr  = (float2*)(ws + (35u << 20));                // 512 KB
  int*            perm = (int*)(ws + (35u << 20) + (512u << 10));    // 256 KB
  unsigned char*  pid  = (unsigned char*)(ws + (35u << 20) + (768u << 10)); // 64 KB
  int*            cnt  = (int*)(ws + (35u << 20) + (832u << 10));    // 256 B
  int*            gcur = (int*)(ws + (35u << 20) + (833u << 10));    // 256 B
  int4*           meta = (int4*)(ws + (35u << 20) + (834u << 10));   // 9.6 KB

  hipFuncSetAttribute((const void*)moe_gemm_pair, hipFuncAttributeMaxDynamicSharedMemorySize, 67584);

  hipMemsetAsync(cnt, 0, 64 * sizeof(int), stream);
  prep_w<<<512, 256, 0, stream>>>(ew, eb, Wb);
  gating<<<4096, 256, 0, stream>>>(x, gw, gb, xbp, cw);
  pairize<<<256, 256, 0, stream>>>(cw, pid, wpr, cnt);
  scan_k<<<1, 64, 0, stream>>>(cnt, gcur, meta);
  scatter_k<<<256, 256, 0, stream>>>(pid, gcur, perm);
  moe_gemm_pair<<<2 * NMETA, 256, 67584, stream>>>(xbp, Wb, wpr, perm, meta, out);
}